// Round 2
// baseline (180.318 us; speedup 1.0000x reference)
//
#include <hip/hip_runtime.h>

#define BB 64
#define CC 128
#define HH 80
#define WW 80
#define HW 6400
#define NH 4
#define HD 32
#define SIG2F 0.18f   // 2 * 0.3^2

// ---------------------------------------------------------------------------
// Kernel A: nearest-resize masks (640->80, = stride-8 sample), store float mask,
// compute binary centroid -> pos, and 1/(float-mask-sum + 1e-6).
// grid: B*2 blocks, 256 threads
// ---------------------------------------------------------------------------
__global__ void mask_kernel(const float* __restrict__ masks,
                            float* __restrict__ m_res,
                            float* __restrict__ pos,
                            float* __restrict__ invms) {
    int plane = blockIdx.x;            // b*2 + n
    int tid = threadIdx.x;
    const float* mp = masks + (size_t)plane * 640 * 640;
    float* mo = m_res + (size_t)plane * HW;
    float fsum = 0.f; int cnt = 0, sy = 0, sx = 0;
    for (int p = tid; p < HW; p += 256) {
        int y = p / WW, x = p - y * WW;
        float v = mp[(size_t)(y * 8) * 640 + x * 8];
        mo[p] = v;
        fsum += v;
        if (v > 0.5f) { cnt++; sy += y; sx += x; }
    }
    __shared__ float rf[256];
    __shared__ int rc[256], ry[256], rx[256];
    rf[tid] = fsum; rc[tid] = cnt; ry[tid] = sy; rx[tid] = sx;
    __syncthreads();
    for (int s = 128; s > 0; s >>= 1) {
        if (tid < s) {
            rf[tid] += rf[tid + s]; rc[tid] += rc[tid + s];
            ry[tid] += ry[tid + s]; rx[tid] += rx[tid + s];
        }
        __syncthreads();
    }
    if (tid == 0) {
        float c = (float)rc[0];
        float cy = (float)ry[0] / c;
        float cx = (float)rx[0] / c;
        pos[plane * 2 + 0] = cx / (float)WW * 2.f - 1.f;   // x in [-1,1]
        pos[plane * 2 + 1] = cy / (float)HH * 2.f - 1.f;   // y in [-1,1]
        invms[plane] = 1.f / (rf[0] + 1e-6f);
    }
}

// ---------------------------------------------------------------------------
// Kernel B: masked average pooling. nodes[b,n,c] = dot(x[b,c,:,:], m[b,n,:,:]) * invms
// grid: B*C blocks, 256 threads, float4 loads
// ---------------------------------------------------------------------------
__global__ void pool_kernel(const float* __restrict__ x,
                            const float* __restrict__ m_res,
                            const float* __restrict__ invms,
                            float* __restrict__ nodes) {
    int blk = blockIdx.x;              // b*128 + c
    int b = blk >> 7, c = blk & 127;
    int tid = threadIdx.x;
    const float4* xp = (const float4*)(x + (size_t)blk * HW);
    const float4* m0 = (const float4*)(m_res + (size_t)(b * 2 + 0) * HW);
    const float4* m1 = (const float4*)(m_res + (size_t)(b * 2 + 1) * HW);
    float s0 = 0.f, s1 = 0.f;
    for (int v = tid; v < HW / 4; v += 256) {
        float4 xv = xp[v];
        float4 a = m0[v], bb = m1[v];
        s0 += xv.x * a.x + xv.y * a.y + xv.z * a.z + xv.w * a.w;
        s1 += xv.x * bb.x + xv.y * bb.y + xv.z * bb.z + xv.w * bb.w;
    }
    // wave-level reduce (wave64), then cross-wave via LDS
    for (int off = 32; off > 0; off >>= 1) {
        s0 += __shfl_down(s0, off, 64);
        s1 += __shfl_down(s1, off, 64);
    }
    __shared__ float r0[4], r1[4];
    int wid = tid >> 6;
    if ((tid & 63) == 0) { r0[wid] = s0; r1[wid] = s1; }
    __syncthreads();
    if (tid == 0) {
        float t0 = r0[0] + r0[1] + r0[2] + r0[3];
        float t1 = r1[0] + r1[1] + r1[2] + r1[3];
        nodes[(size_t)(b * 2 + 0) * 128 + c] = t0 * invms[b * 2 + 0];
        nodes[(size_t)(b * 2 + 1) * 128 + c] = t1 * invms[b * 2 + 1];
    }
}

// ---------------------------------------------------------------------------
// Kernel C: graph attention (N=2, 4 heads x 32) + out-proj + LN + FFN + LN
// grid: B blocks, 128 threads
// ---------------------------------------------------------------------------
__global__ void attn_kernel(const float* __restrict__ nodes, const float* __restrict__ pos,
                            const float* __restrict__ wq, const float* __restrict__ bq,
                            const float* __restrict__ wk, const float* __restrict__ bk,
                            const float* __restrict__ wv, const float* __restrict__ bv,
                            const float* __restrict__ wo, const float* __restrict__ bo,
                            const float* __restrict__ g1, const float* __restrict__ be1,
                            const float* __restrict__ g2, const float* __restrict__ be2,
                            const float* __restrict__ w1, const float* __restrict__ bf1,
                            const float* __restrict__ w2, const float* __restrict__ bf2,
                            float* __restrict__ h2out) {
    int b = blockIdx.x, t = threadIdx.x;
    __shared__ float sn[2][128], sq[2][128], sk[2][128], sv[2][128];
    __shared__ float sao[2][128], sh1[2][128], sf[2][256];
    __shared__ float attn[NH][2][2];
    __shared__ float stat[2][2];        // [n][0]=mu, [n][1]=inv_std
    sn[0][t] = nodes[(size_t)(b * 2 + 0) * 128 + t];
    sn[1][t] = nodes[(size_t)(b * 2 + 1) * 128 + t];
    __syncthreads();
    // q, k, v projections (thread t owns output channel t)
    {
        float q0 = bq[t], q1 = bq[t], k0 = bk[t], k1 = bk[t], v0 = bv[t], v1 = bv[t];
        for (int c = 0; c < 128; c++) {
            float n0 = sn[0][c], n1 = sn[1][c];
            float we;
            we = wq[t * 128 + c]; q0 += n0 * we; q1 += n1 * we;
            we = wk[t * 128 + c]; k0 += n0 * we; k1 += n1 * we;
            we = wv[t * 128 + c]; v0 += n0 * we; v1 += n1 * we;
        }
        sq[0][t] = q0; sq[1][t] = q1;
        sk[0][t] = k0; sk[1][t] = k1;
        sv[0][t] = v0; sv[1][t] = v1;
    }
    __syncthreads();
    // scores - dist
    if (t < 16) {
        int h = t >> 2, n = (t >> 1) & 1, m = t & 1;
        float s = 0.f;
        for (int d = 0; d < HD; d++) s += sq[n][h * HD + d] * sk[m][h * HD + d];
        s *= 0.17677669529663687f;      // 1/sqrt(32)
        float dxp = pos[b * 4 + n * 2 + 0] - pos[b * 4 + m * 2 + 0];
        float dyp = pos[b * 4 + n * 2 + 1] - pos[b * 4 + m * 2 + 1];
        attn[h][n][m] = s - sqrtf(dxp * dxp + dyp * dyp);
    }
    __syncthreads();
    // softmax over m (2 entries)
    if (t < 8) {
        int h = t >> 1, n = t & 1;
        float a0 = attn[h][n][0], a1 = attn[h][n][1];
        float mx = fmaxf(a0, a1);
        float e0 = __expf(a0 - mx), e1 = __expf(a1 - mx);
        float inv = 1.f / (e0 + e1);
        attn[h][n][0] = e0 * inv; attn[h][n][1] = e1 * inv;
    }
    __syncthreads();
    // attention output
    {
        int h = t >> 5;
        sao[0][t] = attn[h][0][0] * sv[0][t] + attn[h][0][1] * sv[1][t];
        sao[1][t] = attn[h][1][0] * sv[0][t] + attn[h][1][1] * sv[1][t];
    }
    __syncthreads();
    // out projection + residual (store res1 into sh1)
    {
        float o0 = bo[t], o1 = bo[t];
        for (int c = 0; c < 128; c++) {
            float w = wo[t * 128 + c];
            o0 += sao[0][c] * w; o1 += sao[1][c] * w;
        }
        sh1[0][t] = sn[0][t] + o0;
        sh1[1][t] = sn[1][t] + o1;
    }
    __syncthreads();
    // LN1
    if (t < 2) {
        float mu = 0.f;
        for (int c = 0; c < 128; c++) mu += sh1[t][c];
        mu *= (1.f / 128.f);
        float var = 0.f;
        for (int c = 0; c < 128; c++) { float d = sh1[t][c] - mu; var += d * d; }
        var *= (1.f / 128.f);
        stat[t][0] = mu; stat[t][1] = rsqrtf(var + 1e-5f);
    }
    __syncthreads();
    {
        float h0 = (sh1[0][t] - stat[0][0]) * stat[0][1] * g1[t] + be1[t];
        float h1 = (sh1[1][t] - stat[1][0]) * stat[1][1] * g1[t] + be1[t];
        sh1[0][t] = h0; sh1[1][t] = h1;   // own slot only; no cross-thread hazard
    }
    __syncthreads();
    // FFN layer 1 (256 outputs, thread t does j = t, t+128)
    for (int jj = 0; jj < 2; jj++) {
        int j = t + jj * 128;
        float a0 = bf1[j], a1 = bf1[j];
        for (int c = 0; c < 128; c++) {
            float w = w1[j * 128 + c];
            a0 += sh1[0][c] * w; a1 += sh1[1][c] * w;
        }
        sf[0][j] = fmaxf(a0, 0.f);
        sf[1][j] = fmaxf(a1, 0.f);
    }
    __syncthreads();
    // FFN layer 2 + residual (store res2 into sao)
    {
        float a0 = bf2[t], a1 = bf2[t];
        for (int j = 0; j < 256; j++) {
            float w = w2[t * 256 + j];
            a0 += sf[0][j] * w; a1 += sf[1][j] * w;
        }
        sao[0][t] = sh1[0][t] + a0;
        sao[1][t] = sh1[1][t] + a1;
    }
    __syncthreads();
    // LN2
    if (t < 2) {
        float mu = 0.f;
        for (int c = 0; c < 128; c++) mu += sao[t][c];
        mu *= (1.f / 128.f);
        float var = 0.f;
        for (int c = 0; c < 128; c++) { float d = sao[t][c] - mu; var += d * d; }
        var *= (1.f / 128.f);
        stat[t][0] = mu; stat[t][1] = rsqrtf(var + 1e-5f);
    }
    __syncthreads();
    h2out[(size_t)(b * 2 + 0) * 128 + t] = (sao[0][t] - stat[0][0]) * stat[0][1] * g2[t] + be2[t];
    h2out[(size_t)(b * 2 + 1) * 128 + t] = (sao[1][t] - stat[1][0]) * stat[1][1] * g2[t] + be2[t];
}

// ---------------------------------------------------------------------------
// Kernel D: separable gaussian splat + residual add.
// out[b,c,y,x] = x[b,c,y,x] + sum_n h2[b,n,c] * wy[n][y] * wx[n][x]
// grid: B*C blocks, 256 threads, float4
// ---------------------------------------------------------------------------
__global__ void splat_kernel(const float* __restrict__ x,
                             const float* __restrict__ h2,
                             const float* __restrict__ pos,
                             float* __restrict__ out) {
    int blk = blockIdx.x;              // b*128 + c
    int b = blk >> 7, c = blk & 127;
    int tid = threadIdx.x;
    __shared__ float wy[2][HH], wx[2][WW];
    float px0 = pos[b * 4 + 0], py0 = pos[b * 4 + 1];
    float px1 = pos[b * 4 + 2], py1 = pos[b * 4 + 3];
    if (tid < HH) {
        float g = -1.f + 2.f * (float)tid / 79.f;   // linspace(-1,1,80)
        float d;
        d = g - py0; wy[0][tid] = __expf(-(d * d) * (1.f / SIG2F));
        d = g - py1; wy[1][tid] = __expf(-(d * d) * (1.f / SIG2F));
        d = g - px0; wx[0][tid] = __expf(-(d * d) * (1.f / SIG2F));
        d = g - px1; wx[1][tid] = __expf(-(d * d) * (1.f / SIG2F));
    }
    float h0 = h2[(size_t)(b * 2 + 0) * 128 + c];
    float h1 = h2[(size_t)(b * 2 + 1) * 128 + c];
    __syncthreads();
    const float4* xp = (const float4*)(x + (size_t)blk * HW);
    float4* op = (float4*)(out + (size_t)blk * HW);
    for (int v = tid; v < HW / 4; v += 256) {
        int y = v / (WW / 4);
        int xq = (v - y * (WW / 4)) * 4;
        float a0 = h0 * wy[0][y], a1 = h1 * wy[1][y];
        float4 xv = xp[v];
        float4 o;
        o.x = xv.x + a0 * wx[0][xq + 0] + a1 * wx[1][xq + 0];
        o.y = xv.y + a0 * wx[0][xq + 1] + a1 * wx[1][xq + 1];
        o.z = xv.z + a0 * wx[0][xq + 2] + a1 * wx[1][xq + 2];
        o.w = xv.w + a0 * wx[0][xq + 3] + a1 * wx[1][xq + 3];
        op[v] = o;
    }
}

// ---------------------------------------------------------------------------
extern "C" void kernel_launch(void* const* d_in, const int* in_sizes, int n_in,
                              void* d_out, int out_size, void* d_ws, size_t ws_size,
                              hipStream_t stream) {
    const float* x     = (const float*)d_in[0];
    const float* masks = (const float*)d_in[1];
    const float* wq = (const float*)d_in[2],  *bq = (const float*)d_in[3];
    const float* wk = (const float*)d_in[4],  *bk = (const float*)d_in[5];
    const float* wv = (const float*)d_in[6],  *bv = (const float*)d_in[7];
    const float* wo = (const float*)d_in[8],  *bo = (const float*)d_in[9];
    const float* g1 = (const float*)d_in[10], *be1 = (const float*)d_in[11];
    const float* g2 = (const float*)d_in[12], *be2 = (const float*)d_in[13];
    const float* w1 = (const float*)d_in[14], *bf1 = (const float*)d_in[15];
    const float* w2 = (const float*)d_in[16], *bf2 = (const float*)d_in[17];
    float* out = (float*)d_out;

    // workspace layout (floats)
    float* ws     = (float*)d_ws;
    float* m_res  = ws;                       // 64*2*6400 = 819200
    float* pos    = ws + 819200;              // 256
    float* invms  = ws + 819456;              // 128
    float* nodes  = ws + 819584;              // 16384
    float* h2     = ws + 835968;              // 16384   (total ~3.4 MB)

    mask_kernel<<<BB * 2, 256, 0, stream>>>(masks, m_res, pos, invms);
    pool_kernel<<<BB * CC, 256, 0, stream>>>(x, m_res, invms, nodes);
    attn_kernel<<<BB, 128, 0, stream>>>(nodes, pos,
                                        wq, bq, wk, bk, wv, bv, wo, bo,
                                        g1, be1, g2, be2, w1, bf1, w2, bf2, h2);
    splat_kernel<<<BB * CC, 256, 0, stream>>>(x, h2, pos, out);
}

// Round 3
// 150.206 us; speedup vs baseline: 1.2005x; 1.2005x over previous
//
#include <hip/hip_runtime.h>

#define BB 64
#define CC 128
#define HH 80
#define WW 80
#define HW 6400
#define SIG2F 0.18f   // 2 * 0.3^2

typedef float f4v __attribute__((ext_vector_type(4)));

// ---------------------------------------------------------------------------
// Kernel A: nearest-resize masks (640->80 = stride-8 sample), store float mask,
// binary centroid -> pos, 1/(float-mask-sum + 1e-6).
// ---------------------------------------------------------------------------
__global__ __launch_bounds__(256) void mask_kernel(const float* __restrict__ masks,
                                                   float* __restrict__ m_res,
                                                   float* __restrict__ pos,
                                                   float* __restrict__ invms) {
    int plane = blockIdx.x;            // b*2 + n
    int tid = threadIdx.x;
    const float* mp = masks + (size_t)plane * 640 * 640;
    float* mo = m_res + (size_t)plane * HW;
    float fsum = 0.f; int cnt = 0, sy = 0, sx = 0;
    for (int p = tid; p < HW; p += 256) {
        int y = p / WW, x = p - y * WW;
        float v = mp[(size_t)(y * 8) * 640 + x * 8];
        mo[p] = v;
        fsum += v;
        if (v > 0.5f) { cnt++; sy += y; sx += x; }
    }
    __shared__ float rf[256];
    __shared__ int rc[256], ry[256], rx[256];
    rf[tid] = fsum; rc[tid] = cnt; ry[tid] = sy; rx[tid] = sx;
    __syncthreads();
    for (int s = 128; s > 0; s >>= 1) {
        if (tid < s) {
            rf[tid] += rf[tid + s]; rc[tid] += rc[tid + s];
            ry[tid] += ry[tid + s]; rx[tid] += rx[tid + s];
        }
        __syncthreads();
    }
    if (tid == 0) {
        float c = (float)rc[0];
        float cy = (float)ry[0] / c;
        float cx = (float)rx[0] / c;
        pos[plane * 2 + 0] = cx / (float)WW * 2.f - 1.f;   // x in [-1,1]
        pos[plane * 2 + 1] = cy / (float)HH * 2.f - 1.f;   // y in [-1,1]
        invms[plane] = 1.f / (rf[0] + 1e-6f);
    }
}

// ---------------------------------------------------------------------------
// Kernel B: masked average pooling. nodes[b,n,c] = dot(x[b,c,:,:], m[b,n,:,:]) * invms
// ---------------------------------------------------------------------------
__global__ __launch_bounds__(256) void pool_kernel(const float* __restrict__ x,
                                                   const float* __restrict__ m_res,
                                                   const float* __restrict__ invms,
                                                   float* __restrict__ nodes) {
    int blk = blockIdx.x;              // b*128 + c
    int b = blk >> 7, c = blk & 127;
    int tid = threadIdx.x;
    const f4v* xp = (const f4v*)(x + (size_t)blk * HW);
    const f4v* m0 = (const f4v*)(m_res + (size_t)(b * 2 + 0) * HW);
    const f4v* m1 = (const f4v*)(m_res + (size_t)(b * 2 + 1) * HW);
    float s0 = 0.f, s1 = 0.f;
    #pragma unroll 2
    for (int v = tid; v < HW / 4; v += 256) {
        f4v xv = xp[v];
        f4v a = m0[v], bb = m1[v];
        s0 += xv.x * a.x + xv.y * a.y + xv.z * a.z + xv.w * a.w;
        s1 += xv.x * bb.x + xv.y * bb.y + xv.z * bb.z + xv.w * bb.w;
    }
    for (int off = 32; off > 0; off >>= 1) {
        s0 += __shfl_down(s0, off, 64);
        s1 += __shfl_down(s1, off, 64);
    }
    __shared__ float r0[4], r1[4];
    int wid = tid >> 6;
    if ((tid & 63) == 0) { r0[wid] = s0; r1[wid] = s1; }
    __syncthreads();
    if (tid == 0) {
        float t0 = r0[0] + r0[1] + r0[2] + r0[3];
        float t1 = r1[0] + r1[1] + r1[2] + r1[3];
        nodes[(size_t)(b * 2 + 0) * 128 + c] = t0 * invms[b * 2 + 0];
        nodes[(size_t)(b * 2 + 1) * 128 + c] = t1 * invms[b * 2 + 1];
    }
}

// ---------------------------------------------------------------------------
// block-wide (128 threads = 2 waves) sum, result broadcast to all threads
// ---------------------------------------------------------------------------
__device__ __forceinline__ float blocksum128(float v, int t, float* red2) {
    for (int off = 32; off > 0; off >>= 1) v += __shfl_down(v, off, 64);
    __syncthreads();                       // protect red2 from previous use
    if ((t & 63) == 0) red2[t >> 6] = v;
    __syncthreads();
    return red2[0] + red2[1];
}

// ---------------------------------------------------------------------------
// Kernel C: graph attention (N=2, 4 heads x 32) + out-proj + LN + FFN + LN
// grid: B blocks, 128 threads
// ---------------------------------------------------------------------------
__global__ __launch_bounds__(128) void attn_kernel(
        const float* __restrict__ nodes, const float* __restrict__ pos,
        const float* __restrict__ wq, const float* __restrict__ bq,
        const float* __restrict__ wk, const float* __restrict__ bk,
        const float* __restrict__ wv, const float* __restrict__ bv,
        const float* __restrict__ wo, const float* __restrict__ bo,
        const float* __restrict__ g1, const float* __restrict__ be1,
        const float* __restrict__ g2, const float* __restrict__ be2,
        const float* __restrict__ w1, const float* __restrict__ bf1,
        const float* __restrict__ w2, const float* __restrict__ bf2,
        float* __restrict__ h2out) {
    int b = blockIdx.x, t = threadIdx.x;
    __shared__ float sn[2][128], sq[2][128], sk[2][128], sv[2][128];
    __shared__ float sao[2][128], sh[2][128], sf[2][256];
    __shared__ float attnw[4][2][2];
    __shared__ float red2[2];
    __shared__ float sdist;
    float n0 = nodes[(size_t)(b * 2 + 0) * 128 + t];
    float n1 = nodes[(size_t)(b * 2 + 1) * 128 + t];
    sn[0][t] = n0; sn[1][t] = n1;
    if (t == 0) {
        float dxp = pos[b * 4 + 0] - pos[b * 4 + 2];
        float dyp = pos[b * 4 + 1] - pos[b * 4 + 3];
        sdist = sqrtf(dxp * dxp + dyp * dyp);
    }
    __syncthreads();
    // QKV projections (thread t owns output channel t, both nodes)
    float q0 = bq[t], q1 = bq[t], k0 = bk[t], k1 = bk[t], v0 = bv[t], v1 = bv[t];
    #pragma unroll 4
    for (int c = 0; c < 128; c++) {
        float a0 = sn[0][c], a1 = sn[1][c];
        float w;
        w = wq[t * 128 + c]; q0 += a0 * w; q1 += a1 * w;
        w = wk[t * 128 + c]; k0 += a0 * w; k1 += a1 * w;
        w = wv[t * 128 + c]; v0 += a0 * w; v1 += a1 * w;
    }
    sv[0][t] = v0; sv[1][t] = v1;
    // scores: head h = t>>5, dim d = t&31; 32-lane shuffle reductions
    {
        float s00 = q0 * k0, s01 = q0 * k1, s10 = q1 * k0, s11 = q1 * k1;
        for (int off = 16; off > 0; off >>= 1) {
            s00 += __shfl_down(s00, off, 32);
            s01 += __shfl_down(s01, off, 32);
            s10 += __shfl_down(s10, off, 32);
            s11 += __shfl_down(s11, off, 32);
        }
        if ((t & 31) == 0) {
            int h = t >> 5;
            const float sc = 0.17677669529663687f;     // 1/sqrt(32)
            float D = sdist;
            // row n=0: logits (s00*sc - 0, s01*sc - D)
            float l0 = s00 * sc, l1 = s01 * sc - D;
            float mx = fmaxf(l0, l1);
            float e0 = __expf(l0 - mx), e1 = __expf(l1 - mx);
            float inv = 1.f / (e0 + e1);
            attnw[h][0][0] = e0 * inv; attnw[h][0][1] = e1 * inv;
            // row n=1: logits (s10*sc - D, s11*sc - 0)
            l0 = s10 * sc - D; l1 = s11 * sc;
            mx = fmaxf(l0, l1);
            e0 = __expf(l0 - mx); e1 = __expf(l1 - mx);
            inv = 1.f / (e0 + e1);
            attnw[h][1][0] = e0 * inv; attnw[h][1][1] = e1 * inv;
        }
    }
    __syncthreads();
    // attention output
    {
        int h = t >> 5;
        sao[0][t] = attnw[h][0][0] * sv[0][t] + attnw[h][0][1] * sv[1][t];
        sao[1][t] = attnw[h][1][0] * sv[0][t] + attnw[h][1][1] * sv[1][t];
    }
    __syncthreads();
    // out projection + residual (registers)
    float o0 = bo[t], o1 = bo[t];
    #pragma unroll 4
    for (int c = 0; c < 128; c++) {
        float w = wo[t * 128 + c];
        o0 += sao[0][c] * w; o1 += sao[1][c] * w;
    }
    float r0 = n0 + o0, r1 = n1 + o1;
    // LN1 (parallel reductions)
    float mu0 = blocksum128(r0, t, red2) * (1.f / 128.f);
    float mu1 = blocksum128(r1, t, red2) * (1.f / 128.f);
    float d0 = r0 - mu0, d1 = r1 - mu1;
    float var0 = blocksum128(d0 * d0, t, red2) * (1.f / 128.f);
    float var1 = blocksum128(d1 * d1, t, red2) * (1.f / 128.f);
    float h0 = d0 * rsqrtf(var0 + 1e-5f) * g1[t] + be1[t];
    float h1 = d1 * rsqrtf(var1 + 1e-5f) * g1[t] + be1[t];
    sh[0][t] = h0; sh[1][t] = h1;
    __syncthreads();
    // FFN layer 1 (256 outputs; thread t does j = t, t+128)
    #pragma unroll
    for (int jj = 0; jj < 2; jj++) {
        int j = t + jj * 128;
        float a0 = bf1[j], a1 = bf1[j];
        #pragma unroll 4
        for (int c = 0; c < 128; c++) {
            float w = w1[j * 128 + c];
            a0 += sh[0][c] * w; a1 += sh[1][c] * w;
        }
        sf[0][j] = fmaxf(a0, 0.f);
        sf[1][j] = fmaxf(a1, 0.f);
    }
    __syncthreads();
    // FFN layer 2 + residual
    float a0 = bf2[t], a1 = bf2[t];
    #pragma unroll 4
    for (int j = 0; j < 256; j++) {
        float w = w2[t * 256 + j];
        a0 += sf[0][j] * w; a1 += sf[1][j] * w;
    }
    float r20 = h0 + a0, r21 = h1 + a1;
    // LN2
    float m20 = blocksum128(r20, t, red2) * (1.f / 128.f);
    float m21 = blocksum128(r21, t, red2) * (1.f / 128.f);
    float e0 = r20 - m20, e1 = r21 - m21;
    float v20 = blocksum128(e0 * e0, t, red2) * (1.f / 128.f);
    float v21 = blocksum128(e1 * e1, t, red2) * (1.f / 128.f);
    h2out[(size_t)(b * 2 + 0) * 128 + t] = e0 * rsqrtf(v20 + 1e-5f) * g2[t] + be2[t];
    h2out[(size_t)(b * 2 + 1) * 128 + t] = e1 * rsqrtf(v21 + 1e-5f) * g2[t] + be2[t];
}

// ---------------------------------------------------------------------------
// Kernel D: separable gaussian splat + residual add.
// out[b,c,y,x] = x[b,c,y,x] + sum_n h2[b,n,c] * wy[n][y] * wx[n][x]
// NT stores for `out` so the L3-resident copy of `x` (cached by pool_kernel)
// is not evicted by the output stream.
// ---------------------------------------------------------------------------
__global__ __launch_bounds__(256) void splat_kernel(const float* __restrict__ x,
                                                    const float* __restrict__ h2,
                                                    const float* __restrict__ pos,
                                                    float* __restrict__ out) {
    int blk = blockIdx.x;              // b*128 + c
    int b = blk >> 7, c = blk & 127;
    int tid = threadIdx.x;
    __shared__ float wy[2][HH], wx[2][WW];
    float px0 = pos[b * 4 + 0], py0 = pos[b * 4 + 1];
    float px1 = pos[b * 4 + 2], py1 = pos[b * 4 + 3];
    if (tid < HH) {
        float g = -1.f + 2.f * (float)tid / 79.f;   // linspace(-1,1,80)
        float d;
        d = g - py0; wy[0][tid] = __expf(-(d * d) * (1.f / SIG2F));
        d = g - py1; wy[1][tid] = __expf(-(d * d) * (1.f / SIG2F));
        d = g - px0; wx[0][tid] = __expf(-(d * d) * (1.f / SIG2F));
        d = g - px1; wx[1][tid] = __expf(-(d * d) * (1.f / SIG2F));
    }
    float h0 = h2[(size_t)(b * 2 + 0) * 128 + c];
    float h1 = h2[(size_t)(b * 2 + 1) * 128 + c];
    __syncthreads();
    const f4v* xp = (const f4v*)(x + (size_t)blk * HW);
    f4v* op = (f4v*)(out + (size_t)blk * HW);
    #pragma unroll 2
    for (int v = tid; v < HW / 4; v += 256) {
        int y = v / (WW / 4);
        int xq = (v - y * (WW / 4)) * 4;
        float a0 = h0 * wy[0][y], a1 = h1 * wy[1][y];
        f4v xv = xp[v];
        f4v o;
        o.x = xv.x + a0 * wx[0][xq + 0] + a1 * wx[1][xq + 0];
        o.y = xv.y + a0 * wx[0][xq + 1] + a1 * wx[1][xq + 1];
        o.z = xv.z + a0 * wx[0][xq + 2] + a1 * wx[1][xq + 2];
        o.w = xv.w + a0 * wx[0][xq + 3] + a1 * wx[1][xq + 3];
        __builtin_nontemporal_store(o, op + v);
    }
}

// ---------------------------------------------------------------------------
extern "C" void kernel_launch(void* const* d_in, const int* in_sizes, int n_in,
                              void* d_out, int out_size, void* d_ws, size_t ws_size,
                              hipStream_t stream) {
    const float* x     = (const float*)d_in[0];
    const float* masks = (const float*)d_in[1];
    const float* wq = (const float*)d_in[2],  *bq = (const float*)d_in[3];
    const float* wk = (const float*)d_in[4],  *bk = (const float*)d_in[5];
    const float* wv = (const float*)d_in[6],  *bv = (const float*)d_in[7];
    const float* wo = (const float*)d_in[8],  *bo = (const float*)d_in[9];
    const float* g1 = (const float*)d_in[10], *be1 = (const float*)d_in[11];
    const float* g2 = (const float*)d_in[12], *be2 = (const float*)d_in[13];
    const float* w1 = (const float*)d_in[14], *bf1 = (const float*)d_in[15];
    const float* w2 = (const float*)d_in[16], *bf2 = (const float*)d_in[17];
    float* out = (float*)d_out;

    // workspace layout (floats)
    float* ws     = (float*)d_ws;
    float* m_res  = ws;                       // 64*2*6400 = 819200
    float* pos    = ws + 819200;              // 256
    float* invms  = ws + 819456;              // 128
    float* nodes  = ws + 819584;              // 16384
    float* h2     = ws + 835968;              // 16384   (total ~3.4 MB)

    mask_kernel<<<BB * 2, 256, 0, stream>>>(masks, m_res, pos, invms);
    pool_kernel<<<BB * CC, 256, 0, stream>>>(x, m_res, invms, nodes);
    attn_kernel<<<BB, 128, 0, stream>>>(nodes, pos,
                                        wq, bq, wk, bk, wv, bv, wo, bo,
                                        g1, be1, g2, be2, w1, bf1, w2, bf2, h2);
    splat_kernel<<<BB * CC, 256, 0, stream>>>(x, h2, pos, out);
}